// Round 1
// baseline (262.824 us; speedup 1.0000x reference)
//
#include <hip/hip_runtime.h>
#include <math.h>

// 19-qubit statevector sim. Wire w <-> global bit (18-w).
// Block bits: wires 0..7 (edge qubits) -> block index bit (7-w).
// Local 11 bits: wires 8..18 -> local bit (18-w). 2048 amps/block.
// anc2(18)->bit0, anc1(17)->bit1, neighbor(9+i)->bit(9-i), center(8)->bit10,
// measured wire 10 -> bit 8 (reference measures axis N-1-center = axis 10!).

struct cplx { float x, y; };
__device__ __forceinline__ cplx cmul(cplx a, cplx b){ return {a.x*b.x - a.y*b.y, a.x*b.y + a.y*b.x}; }
__device__ __forceinline__ cplx cadd(cplx a, cplx b){ return {a.x+b.x, a.y+b.y}; }
__device__ __forceinline__ cplx ldc(float2 v){ return {v.x, v.y}; }
__device__ __forceinline__ float2 stc(cplx v){ return make_float2(v.x, v.y); }

__device__ __forceinline__ void mat2mul(const cplx* A, const cplx* B, cplx* C){
  C[0] = cadd(cmul(A[0],B[0]), cmul(A[1],B[2]));
  C[1] = cadd(cmul(A[0],B[1]), cmul(A[1],B[3]));
  C[2] = cadd(cmul(A[2],B[0]), cmul(A[3],B[2]));
  C[3] = cadd(cmul(A[2],B[1]), cmul(A[3],B[3]));
}
__device__ void mk_rz(float t, cplx* M){ float s,c; sincosf(0.5f*t,&s,&c); M[0]={c,-s};M[1]={0,0};M[2]={0,0};M[3]={c,s}; }
__device__ void mk_ry(float t, cplx* M){ float s,c; sincosf(0.5f*t,&s,&c); M[0]={c,0};M[1]={-s,0};M[2]={s,0};M[3]={c,0}; }
__device__ void mk_rx(float t, cplx* M){ float s,c; sincosf(0.5f*t,&s,&c); M[0]={c,0};M[1]={0,-s};M[2]={0,-s};M[3]={c,0}; }
// psi <- Rx(p2) Ry(p1) Rz(p0) psi
__device__ void mk_strong(const float* p, cplx* M){
  cplx Rz[4],Ry[4],Rx[4],T[4];
  mk_rz(p[0],Rz); mk_ry(p[1],Ry); mk_rx(p[2],Rx);
  mat2mul(Ry,Rz,T); mat2mul(Rx,T,M);
}
// psi <- Rz(tz) Ry(ty) psi
__device__ void mk_ryrz(float ty, float tz, cplx* M){
  cplx Rz[4],Ry[4]; mk_rz(tz,Rz); mk_ry(ty,Ry); mat2mul(Rz,Ry,M);
}

// 1q gate on local bit beta of one chunk; if condBit>=0 apply only where that bit==1
__device__ void g1(float2* ch, int beta, const cplx* U, int condBit){
  for (int p = threadIdx.x; p < 1024; p += 256){
    int l0 = ((p >> beta) << (beta+1)) | (p & ((1<<beta)-1));
    if (condBit >= 0 && (((l0 >> condBit) & 1) == 0)) continue;
    int l1 = l0 | (1 << beta);
    cplx a = ldc(ch[l0]), c = ldc(ch[l1]);
    ch[l0] = stc(cadd(cmul(U[0],a), cmul(U[1],c)));
    ch[l1] = stc(cadd(cmul(U[2],a), cmul(U[3],c)));
  }
}
// X gate (pair swap) on local bit beta; optional condition bit
__device__ void xg(float2* ch, int beta, int condBit){
  for (int p = threadIdx.x; p < 1024; p += 256){
    int l0 = ((p >> beta) << (beta+1)) | (p & ((1<<beta)-1));
    if (condBit >= 0 && (((l0 >> condBit) & 1) == 0)) continue;
    int l1 = l0 | (1 << beta);
    float2 t = ch[l0]; ch[l0] = ch[l1]; ch[l1] = t;
  }
}

// Gate table indices:
// 0: U_init,i = Rz(adj[i,1])Ry(adj[i,0])   (cross-chunk mix)
// 1: Rx(inits0)  2: Ry(inits1)  3: Rz(inits2)  4: Ry(inits3)
// 5,6,7:  strong0 fused rotations (qi=0 edge / 1 neighbor / 2 anc1)
// 8,9,10: strong1 fused rotations (qi=0 anc1 / 1 neighbor / 2 anc2)
// 11..19: vert inits v=0..8 (pass 0 only)
// 20,21,22: update fused rotations (pass 7 only)

__global__ __launch_bounds__(256)
void qpass(int pass, const float* __restrict__ inf, const float* __restrict__ inits,
           const float* __restrict__ s0p, const float* __restrict__ s1p,
           const float* __restrict__ up,
           const float2* __restrict__ bufIn, float2* __restrict__ bufOut,
           float* __restrict__ out)
{
  __shared__ float2 c0[2048], c1[2048];
  __shared__ cplx G[23][4];
  __shared__ float wsum[4];
  const int tid = threadIdx.x;
  const int b = blockIdx.x;
  const int i = pass;
  const int mask = 1 << (7 - i);
  const int nb = 9 - i;                 // neighbor local bit

  if (tid < 23) {
    cplx* M = G[tid];
    if      (tid == 0) mk_ryrz(inf[2*i], inf[2*i+1], M);
    else if (tid == 1) mk_rx(inits[0], M);
    else if (tid == 2) mk_ry(inits[1], M);
    else if (tid == 3) mk_rz(inits[2], M);
    else if (tid == 4) mk_ry(inits[3], M);
    else if (tid <= 7)  mk_strong(s0p + (tid-5)*3, M);
    else if (tid <= 10) mk_strong(s1p + (tid-8)*3, M);
    else if (tid <= 19) { int v = tid - 11; mk_ryrz(inf[16+2*v], inf[17+2*v], M); }
    else mk_strong(up + (tid-20)*3, M);
  }

  if (pass == 0) {
    for (int l = tid; l < 2048; l += 256){ c0[l] = make_float2(0.f,0.f); c1[l] = make_float2(0.f,0.f); }
    __syncthreads();
    if (tid == 0 && (b & ~mask) == 0) c0[0] = make_float2(1.f, 0.f);
  } else {
    const int b0 = b & ~mask, b1 = b | mask;
    for (int l = tid; l < 2048; l += 256){ c0[l] = bufIn[(b0<<11)+l]; c1[l] = bufIn[(b1<<11)+l]; }
  }
  __syncthreads();

  if (pass == 0) { // initial vert rotations, wires 8..16 -> bits 10..2
    for (int v = 0; v < 9; v++){ g1(c0, 10-v, G[11+v], -1); g1(c1, 10-v, G[11+v], -1); __syncthreads(); }
  }

  // B: U_init,i on wire i (cross-chunk pointwise mix)
  for (int l = tid; l < 2048; l += 256){
    cplx a = ldc(c0[l]), bb = ldc(c1[l]);
    c0[l] = stc(cadd(cmul(G[0][0],a), cmul(G[0][1],bb)));
    c1[l] = stc(cadd(cmul(G[0][2],a), cmul(G[0][3],bb)));
  }
  __syncthreads();
  // C: CRx(neighbor -> anc1)
  g1(c0, 1, G[1], nb); g1(c1, 1, G[1], nb); __syncthreads();
  // D: CRy(edge -> anc1): only wire-i=1 chunk
  g1(c1, 1, G[2], -1); __syncthreads();
  // E: CRz(neighbor -> anc2)
  g1(c0, 0, G[3], nb); g1(c1, 0, G[3], nb); __syncthreads();
  // F: CRy(edge -> anc2): only c1
  g1(c1, 0, G[4], -1); __syncthreads();
  // strong0 rotations: edge wire (cross-chunk mix), neighbor, anc1
  for (int l = tid; l < 2048; l += 256){
    cplx a = ldc(c0[l]), bb = ldc(c1[l]);
    c0[l] = stc(cadd(cmul(G[5][0],a), cmul(G[5][1],bb)));
    c1[l] = stc(cadd(cmul(G[5][2],a), cmul(G[5][3],bb)));
  }
  __syncthreads();
  g1(c0, nb, G[6], -1); g1(c1, nb, G[6], -1); __syncthreads();
  g1(c0, 1,  G[7], -1); g1(c1, 1,  G[7], -1); __syncthreads();
  // CNOT(edge -> neighbor): X on nb in c1 only
  xg(c1, nb, -1); __syncthreads();
  // CNOT(neighbor -> anc1)
  xg(c0, 1, nb); xg(c1, 1, nb); __syncthreads();
  // CNOT(anc1 -> edge): swap chunks where anc1(bit1)==1
  for (int l = tid; l < 2048; l += 256){
    if ((l >> 1) & 1){ float2 t = c0[l]; c0[l] = c1[l]; c1[l] = t; }
  }
  __syncthreads();
  // strong1 rotations: anc1, neighbor, anc2
  g1(c0, 1,  G[8],  -1); g1(c1, 1,  G[8],  -1); __syncthreads();
  g1(c0, nb, G[9],  -1); g1(c1, nb, G[9],  -1); __syncthreads();
  g1(c0, 0,  G[10], -1); g1(c1, 0,  G[10], -1); __syncthreads();
  // CNOT(anc1 -> neighbor)
  xg(c0, nb, 1); xg(c1, nb, 1); __syncthreads();
  // CNOT(neighbor -> anc2)
  xg(c0, 0, nb); xg(c1, 0, nb); __syncthreads();
  // CNOT(anc2 -> anc1)
  xg(c0, 1, 0); xg(c1, 1, 0); __syncthreads();

  float2* cm = (b & mask) ? c1 : c0;

  if (pass == 7) {
    // update strong block on [center(bit10), anc1(bit1), anc2(bit0)]
    g1(cm, 10, G[20], -1); __syncthreads();
    g1(cm, 1,  G[21], -1); __syncthreads();
    g1(cm, 0,  G[22], -1); __syncthreads();
    xg(cm, 1, 10); __syncthreads();   // CNOT(center -> anc1)
    xg(cm, 0, 1);  __syncthreads();   // CNOT(anc1 -> anc2)
    xg(cm, 10, 0); __syncthreads();   // CNOT(anc2 -> center)
    const float r = 0.70710678118654752f;
    cplx HH[4] = {{r,0.f},{r,0.f},{r,0.f},{-r,0.f}};
    g1(cm, 10, HH, -1); __syncthreads();
    // <Z on wire 10> = sum |amp|^2 * (bit8 ? -1 : +1)
    float s = 0.f;
    for (int l = tid; l < 2048; l += 256){
      float2 v = cm[l];
      float p2 = v.x*v.x + v.y*v.y;
      s += ((l >> 8) & 1) ? -p2 : p2;
    }
    for (int off = 32; off > 0; off >>= 1) s += __shfl_down(s, off);
    int wid = tid >> 6, lane = tid & 63;
    if (lane == 0) wsum[wid] = s;
    __syncthreads();
    if (tid == 0) atomicAdd(out, wsum[0]+wsum[1]+wsum[2]+wsum[3]);
  } else {
    for (int l = tid; l < 2048; l += 256) bufOut[(b<<11)+l] = cm[l];
  }
}

extern "C" void kernel_launch(void* const* d_in, const int* in_sizes, int n_in,
                              void* d_out, int out_size, void* d_ws, size_t ws_size,
                              hipStream_t stream) {
  const float* inf   = (const float*)d_in[0];
  const float* inits = (const float*)d_in[1];
  const float* s0p   = (const float*)d_in[2];
  const float* s1p   = (const float*)d_in[3];
  const float* up    = (const float*)d_in[4];
  float* out = (float*)d_out;
  float2* bufA = (float2*)d_ws;
  float2* bufB = bufA + (1 << 19);

  hipMemsetAsync(out, 0, sizeof(float), stream);
  for (int p = 0; p < 8; p++) {
    const float2* bin = (p & 1) ? bufA : bufB;  // pass p reads buf[(p+1)&1]
    float2* bout      = (p & 1) ? bufB : bufA;  // writes buf[p&1]
    qpass<<<dim3(256), dim3(256), 0, stream>>>(p, inf, inits, s0p, s1p, up, bin, bout, out);
  }
}